// Round 16
// baseline (111.296 us; speedup 1.0000x reference)
//
#include <hip/hip_runtime.h>
#include <hip/hip_bf16.h>

#define NN  512    // data grid / coefficient count per axis
#define NE  1024   // eval points per axis
#define NBC 64     // batch * channels
#define WH  6      // truncated-inverse half width (0.268^7 ~ 1e-4 rel err)
#define WT  13     // 2*WH+1 taps
#define YT  64     // y-tile per eval block

typedef float v4f __attribute__((ext_vector_type(4)));

// ================= compile-time table generation =================
// x = float32 linspace(-1,1,512); knots via float32 cumsum sliding mean;
// basis via de Boor in double; banded LU in double; truncated inverse band
// Gb (half-width 6) for BOTH solve directions; W3T = 4-tap eval basis
// re-anchored to a per-quad aligned 12-tap window, stored TRANSPOSED for
// lane-coalesced loads. Gb rows and W3T have EXACT ZEROS at tap positions
// whose source column falls outside the true span — boundary handling is
// address clamping + zero taps.

struct Tables {
  float Gb[NN][WT];      // truncated A^-1 band
  int   espan[NE];
  float ebas[NE * 4];    // y-combine weights (float4-aligned)
  float W3T[12][NE];     // anchored 4-tap x-filter, transposed
};

constexpr int cfindspan(double u, const float* t) {
  if (u >= (double)t[NN]) return NN - 1;          // t[512] == 1.0
  int lo = 3, hi = NN - 1;
  while (lo < hi) {
    int mid = (lo + hi + 1) >> 1;
    if ((double)t[mid] <= u) lo = mid; else hi = mid - 1;
  }
  return lo;
}

constexpr void cdeboor4(double u, const float* t, int s, double* N) {
  double left[4] = {}, right[4] = {};
  N[0] = 1.0; N[1] = 0.0; N[2] = 0.0; N[3] = 0.0;
  for (int d = 1; d <= 3; ++d) {
    left[d]  = u - (double)t[s + 1 - d];
    right[d] = (double)t[s + d] - u;
    double saved = 0.0;
    for (int r = 0; r < d; ++r) {
      double temp = N[r] / (right[r + 1] + left[d - r]);
      N[r] = saved + right[r + 1] * temp;
      saved = left[d - r] * temp;
    }
    N[d] = saved;
  }
}

constexpr Tables make_tables() {
  Tables T{};
  float x[NN] = {};
  for (int i = 0; i < NN; ++i) x[i] = (float)(-1.0 + (2.0 * i) / 511.0);
  x[0] = -1.0f; x[NN - 1] = 1.0f;
  float t[NN + 4] = {};
  {
    float cs[NN + 1] = {};
    for (int i = 0; i < NN; ++i) cs[i + 1] = cs[i] + x[i];
    for (int i = 0; i < NN - 4; ++i) t[4 + i] = (cs[4 + i] - cs[1 + i]) / 3.0f;
    for (int i = 0; i < 4; ++i) { t[i] = -1.0f; t[NN + i] = 1.0f; }
  }
  double W[NN][7] = {};
  for (int r = 0; r < NN; ++r) {
    double u = (double)x[r];
    int s = cfindspan(u, t);
    double N[4] = {};
    cdeboor4(u, t, s, N);
    for (int dd = 0; dd < 4; ++dd) W[r][s - r + dd] += N[dd];
  }
  for (int r = 0; r < NN; ++r) {
    double rd = 1.0 / W[r][3];
    for (int k = 1; k <= 3; ++k) {
      if (r + k < NN) {
        double l = W[r + k][3 - k] * rd;
        W[r + k][3 - k] = l;
        for (int cc = 1; cc <= 3; ++cc) W[r + k][3 - k + cc] -= l * W[r][3 + cc];
      }
    }
  }
  // truncated inverse band (half-width WH)
  double Gbd[NN][WT] = {};
  double tv[WT] = {};
  for (int pass = 0; pass < 3; ++pass) {
    const int ylo = (pass == 0) ? 0 : (pass == 1) ? 480 : 256;
    const int yhi = (pass == 0) ? 32 : (pass == 1) ? 512 : 257;
    for (int y = ylo; y < yhi; ++y) {
      double wv[21] = {};
      int rend = y + 20; if (rend > NN - 1) rend = NN - 1;
      wv[0] = 1.0;
      for (int r = y + 1; r <= rend; ++r) {
        double acc = 0.0;
        if (r - 1 >= y) acc += W[r][2] * wv[r - 1 - y];
        if (r - 2 >= y) acc += W[r][1] * wv[r - 2 - y];
        if (r - 3 >= y) acc += W[r][0] * wv[r - 3 - y];
        wv[r - y] = -acc;
      }
      double g[33] = {};
      int glo = y - WH; if (glo < 0) glo = 0;
      for (int r = rend; r >= glo; --r) {
        double acc = (r >= y) ? wv[r - y] : 0.0;
        if (r + 1 <= rend) acc -= W[r][4] * g[r + 1 - (y - WH)];
        if (r + 2 <= rend) acc -= W[r][5] * g[r + 2 - (y - WH)];
        if (r + 3 <= rend) acc -= W[r][6] * g[r + 3 - (y - WH)];
        g[r - (y - WH)] = acc / W[r][3];
      }
      if (pass == 2) {
        for (int d = 0; d < WT; ++d) tv[d] = g[2 * WH - d];   // Ainv[256+WH-d][256]
      } else {
        int jlo = y - WH; if (jlo < 0) jlo = 0;
        int jhi = y + WH; if (jhi > NN - 1) jhi = NN - 1;
        for (int j = jlo; j <= jhi; ++j) {
          const bool bdry = (pass == 0) ? (j < 24) : (j >= 488);
          if (bdry) Gbd[j][y - j + WH] = g[j - (y - WH)];
        }
      }
    }
  }
  for (int j = 24; j < 488; ++j)
    for (int d = 0; d < WT; ++d) Gbd[j][d] = tv[d];
  for (int j = 0; j < NN; ++j)
    for (int d = 0; d < WT; ++d) T.Gb[j][d] = (float)Gbd[j][d];
  // eval-point basis + anchored transposed 12-tap x-filter
  int    s_all[NE] = {};
  double dN[NE][4] = {};
  for (int i = 0; i < NE; ++i) {
    float xe = (float)(-1.0 + (2.0 * i) / 1023.0);
    if (i == 0) xe = -1.0f;
    if (i == NE - 1) xe = 1.0f;
    double u = (double)xe;
    int s = cfindspan(u, t);
    double N[4] = {};
    cdeboor4(u, t, s, N);
    s_all[i] = s;
    for (int k = 0; k < 4; ++k) dN[i][k] = N[k];
    T.espan[i] = s;
    T.ebas[i * 4 + 0] = (float)N[0];
    T.ebas[i * 4 + 1] = (float)N[1];
    T.ebas[i * 4 + 2] = (float)N[2];
    T.ebas[i * 4 + 3] = (float)N[3];
  }
  // W3T[m][x]: out[x] = sum_m W3T[m][x] * CTrow[a3 + m], a3 = (s_all[quad0]-3)&~3.
  for (int xx = 0; xx < NE; ++xx) {
    const int a3 = (s_all[(xx >> 2) << 2] - 3) & ~3;
    for (int k = 0; k < 4; ++k) {
      const int m = s_all[xx] - 3 + k - a3;
      T.W3T[m][xx] = (float)dN[xx][k];
    }
  }
  return T;
}

__constant__ Tables g_tab = make_tables();

__device__ __forceinline__ unsigned short f2bf(float f) {
  __hip_bfloat16 h = __float2bfloat16(f);              // round-to-nearest-even
  return reinterpret_cast<const unsigned short&>(h);
}

// ------------- K1: full 2D banded solve, register-staged stage 1 -------------
// CT[bc][j][i] (BF16) = sum_{d,e} Gb[i][d]*Gb[j][e]*Z[bc][i-WH+d][j-WH+e]
// Stage 1 reads Z windows DIRECTLY from global (coalesced 256B groups, L1/L2
// served redundancy); boundary = address clamp + zero taps. 13-tap window for
// j-quad q: w[q+2..q+14] of the 20-float granule window based at quad-8.
// Only LDS is the transposed stage-1 At (22.8 KB) -> 1 barrier.

__global__ __launch_bounds__(256) void k_solve2d(const float* __restrict__ Z,
                                                 unsigned short* __restrict__ CT) {
  const int it = blockIdx.x * 64;
  const int jt = blockIdx.y * 64;
  const int bc = blockIdx.z;
  const float* __restrict__ src = Z + (size_t)bc * (NN * NN);
  __shared__ float At[64][89];   // stage-1 result TRANSPOSED: At[jc][ii]
  const int tid = threadIdx.x;
  const int q4 = (tid & 15) * 4;    // quad base (jc for stage1, ic for stage2)

  { // stage 1: 13-tap along j, 80 i-rows, straight from global
    float cy[4][WT];
    #pragma unroll
    for (int q = 0; q < 4; ++q)
      #pragma unroll
      for (int d = 0; d < WT; ++d)
        cy[q][d] = g_tab.Gb[jt + q4 + q][d];
    #pragma unroll 1
    for (int p = 0; p < 5; ++p) {
      const int ii = p * 16 + (tid >> 4);
      int gi = it - 8 + ii;
      gi = (gi < 0) ? 0 : ((gi > NN - 1) ? NN - 1 : gi);   // clamp: garbage killed by stage-2 zero taps
      const float* __restrict__ rowp = &src[(size_t)gi * NN];
      float w[20];
      #pragma unroll
      for (int e = 0; e < 5; ++e) {
        int gj = jt + q4 - 8 + e * 4;                       // 4-aligned granule
        gj = (gj < 0) ? 0 : ((gj > NN - 4) ? NN - 4 : gj);  // clamp: dead granules hit zero taps
        *(float4*)&w[e * 4] = *(const float4*)&rowp[gj];
      }
      float4 a = make_float4(0.f, 0.f, 0.f, 0.f);
      #pragma unroll
      for (int d = 0; d < WT; ++d) {
        a.x += cy[0][d] * w[2 + d];
        a.y += cy[1][d] * w[3 + d];
        a.z += cy[2][d] * w[4 + d];
        a.w += cy[3][d] * w[5 + d];
      }
      At[q4 + 0][ii] = a.x;
      At[q4 + 1][ii] = a.y;
      At[q4 + 2][ii] = a.z;
      At[q4 + 3][ii] = a.w;
    }
  }
  { // stage 2: 13-tap along i; coalesced bf16 writes
    float cx[4][WT];
    #pragma unroll
    for (int q = 0; q < 4; ++q)
      #pragma unroll
      for (int d = 0; d < WT; ++d)
        cx[q][d] = g_tab.Gb[it + q4 + q][d];
    __syncthreads();
    unsigned short* __restrict__ dst = CT + (size_t)bc * (NN * NN);
    #pragma unroll 1
    for (int p = 0; p < 4; ++p) {
      const int jc = p * 16 + (tid >> 4);
      float w[20];
      #pragma unroll
      for (int e = 0; e < 5; ++e)
        *(float4*)&w[e * 4] = *(const float4*)&At[jc][q4 + e * 4];
      float4 a = make_float4(0.f, 0.f, 0.f, 0.f);
      #pragma unroll
      for (int d = 0; d < WT; ++d) {
        a.x += cx[0][d] * w[2 + d];
        a.y += cx[1][d] * w[3 + d];
        a.z += cx[2][d] * w[4 + d];
        a.w += cx[3][d] * w[5 + d];
      }
      ushort4 o;
      o.x = f2bf(a.x); o.y = f2bf(a.y); o.z = f2bf(a.z); o.w = f2bf(a.w);
      *(ushort4*)&dst[(size_t)(jt + jc) * NN + it + q4] = o;   // 8B aligned
    }
  }
}

// ------------- K2: LDS-FREE sliding P-window eval (bf16 CT) -------------
// P[r] = anchored 12-tap x-filter of CT row r at this thread's x-quad,
// read DIRECTLY from global (3x dwordx2, ~3x inter-lane overlap -> L1/L2
// broadcast; unique bytes unchanged). out[y] = 4-tap y-combine + float4
// store. No LDS, no barrier, pure streaming; slides are block-uniform.

__global__ __launch_bounds__(256) void k_eval9(const unsigned short* __restrict__ CT,
                                               float* __restrict__ out) {
  const int b = blockIdx.x;                         // 16 y-tiles
  const int ytile = ((b & 7) << 1) | (b >> 3);      // XCD-chunked swizzle (bijective, 16)
  const int y0 = ytile * YT;
  const int bc = blockIdx.y;
  const unsigned short* __restrict__ S = CT + (size_t)bc * (NN * NN);
  const int tid = threadIdx.x;

  // hoisted per-thread constants (lane-coalesced via transposed W3T)
  const int x0 = tid * 4;
  const int a3 = (g_tab.espan[x0] - 3) & ~3;        // window base (mult of 4 -> 8B aligned)
  float tp[4][12];
  #pragma unroll
  for (int m = 0; m < 12; ++m)
    #pragma unroll
    for (int e = 0; e < 4; ++e)
      tp[e][m] = g_tab.W3T[m][x0 + e];

  // filtered quad of global CT row r (rows needed are <= espan[1023] <= 511).
  // Reads may overrun row end by <= 8 elems: in-buffer, killed by zero taps.
  auto filterP = [&](int r) -> v4f {
    const unsigned short* __restrict__ rp = &S[(size_t)r * NN + a3];
    uint2 q0 = *(const uint2*)&rp[0];
    uint2 q1 = *(const uint2*)&rp[4];
    uint2 q2 = *(const uint2*)&rp[8];
    float w[12];
    w[0]  = __uint_as_float(q0.x << 16); w[1]  = __uint_as_float(q0.x & 0xffff0000u);
    w[2]  = __uint_as_float(q0.y << 16); w[3]  = __uint_as_float(q0.y & 0xffff0000u);
    w[4]  = __uint_as_float(q1.x << 16); w[5]  = __uint_as_float(q1.x & 0xffff0000u);
    w[6]  = __uint_as_float(q1.y << 16); w[7]  = __uint_as_float(q1.y & 0xffff0000u);
    w[8]  = __uint_as_float(q2.x << 16); w[9]  = __uint_as_float(q2.x & 0xffff0000u);
    w[10] = __uint_as_float(q2.y << 16); w[11] = __uint_as_float(q2.y & 0xffff0000u);
    v4f p;
    #pragma unroll
    for (int e = 0; e < 4; ++e) {
      float s0 = 0.f, s1 = 0.f;
      #pragma unroll
      for (int m = 0; m < 12; m += 2) {
        s0 += tp[e][m]     * w[m];
        s1 += tp[e][m + 1] * w[m + 1];
      }
      p[e] = s0 + s1;
    }
    return p;
  };

  // initial window: rows espan(y0)-3 .. espan(y0)
  int prev = g_tab.espan[y0];
  v4f P0 = filterP(prev - 3), P1 = filterP(prev - 2),
      P2 = filterP(prev - 1), P3 = filterP(prev);
  float* __restrict__ O0 = out + ((size_t)bc * NE + y0) * NE + x0;
  #pragma unroll 1
  for (int k = 0; k < YT; ++k) {
    const int ry = g_tab.espan[y0 + k];             // block-uniform; advances 0 or 1
    if (ry != prev) {                               // slide window (static moves)
      P0 = P1; P1 = P2; P2 = P3;
      P3 = filterP(ry);
      prev = ry;
    }
    const float4 wy = *(const float4*)&g_tab.ebas[(y0 + k) * 4];
    v4f o;
    #pragma unroll
    for (int e = 0; e < 4; ++e)
      o[e] = wy.x * P0[e] + wy.y * P1[e] + wy.z * P2[e] + wy.w * P3[e];
    *(v4f*)&O0[(size_t)k * NE] = o;
  }
}

// ---------------- host launcher ----------------

extern "C" void kernel_launch(void* const* d_in, const int* in_sizes, int n_in,
                              void* d_out, int out_size, void* d_ws, size_t ws_size,
                              hipStream_t stream) {
  (void)in_sizes; (void)n_in; (void)out_size; (void)ws_size;
  const float* Z = (const float*)d_in[0];
  float* out = (float*)d_out;
  unsigned short* CT = (unsigned short*)d_ws;   // 32 MB bf16 coefficients

  k_solve2d<<<dim3(8, 8, NBC),    256, 0, stream>>>(Z,  CT);   // 2D banded solve -> bf16 CT
  k_eval9  <<<dim3(NE / YT, NBC), 256, 0, stream>>>(CT, out);  // LDS-free sliding-P eval
}